// Round 6
// baseline (219.993 us; speedup 1.0000x reference)
//
#include <hip/hip_runtime.h>
#include <hip/hip_bf16.h>
#include <cstdint>

// EdgeMLP: score = W3 @ sig(W2 @ sig(W1 @ [h1_u,h1_v,h2_u,h2_u] + b1) + b2) + b3
// Factored: z1 = Anode[src] + Bnode[dst]  (A/B stored bf16, PERMUTED col order:
//   dword slot d of a row holds true cols (32*(d>>4) + (d&15), +16) as (lo,hi);
//   compensated in W2F's k-index in prep).
// R13: R12 (barrier-free, per-wave-owned edges) was still ~41 µs: latency-bound
//   at 2 waves/SIMD because the 128-VGPR register-resident W2F capped occupancy.
//   W2F is identical across waves -> move it to LDS (32KB/block, one-time
//   cooperative load + single barrier; loop remains barrier-free), read B-frags
//   via ds_read_b128 in the nt loop. Frees ~128 VGPR -> __launch_bounds__(256,4)
//   = 4 waves/SIMD. Also: fuse commit->ds_bpermute (da dies instantly), and
//   issue next-tile gathers BEFORE the MFMA+epilogue phase for more cover.
//   Spill tripwire: if WRITE_SIZE balloons (R10 lesson), revert to (256,3).

typedef __attribute__((ext_vector_type(8))) short bf16x8;
typedef __attribute__((ext_vector_type(4))) float f32x4;
typedef __attribute__((ext_vector_type(4))) int   i32x4;

__device__ __forceinline__ float sigmoid_fast(float x) {
    float e = __expf(-x);                       // v_mul + v_exp
    return __builtin_amdgcn_rcpf(1.0f + e);     // v_add + v_rcp  (~1 ulp)
}
__device__ __forceinline__ ushort f2bf_rne(float f) {      // prep path only
    uint32_t u = __float_as_uint(f);
    return (ushort)((u + 0x7fffu + ((u >> 16) & 1u)) >> 16);
}
__device__ __forceinline__ float bf2f_lo(uint32_t d) { return __uint_as_float(d << 16); }
__device__ __forceinline__ float bf2f_hi(uint32_t d) { return __uint_as_float(d & 0xffff0000u); }
__device__ __forceinline__ uint32_t packbf_rhu(float x, float y) {   // round-half-up
    return ((__float_as_uint(x) + 0x8000u) >> 16) |
           ((__float_as_uint(y) + 0x8000u) & 0xffff0000u);
}

// ---------- prep: weights -> bf16 MFMA B-fragment layouts ----------
// frag idx: ((kk*8+nt)*64+lane)*8 + j ; n = nt*16+(lane&15) ; kpos = kk*32+(lane>>4)*8+j
// WCF/WBF use true k = kpos. W2F uses permuted ktrue to match A/B dword packing.
__global__ void prep_kernel(const float* __restrict__ W1, const float* __restrict__ W2,
                            ushort* __restrict__ WCF, ushort* __restrict__ WBF,
                            ushort* __restrict__ W2F) {
    int i = blockIdx.x * blockDim.x + threadIdx.x;
    if (i >= 16384) return;
    int j = i & 7, lf = (i >> 3) & 63, nt = (i >> 9) & 7, kk = i >> 12;
    int n = nt * 16 + (lf & 15);
    int kpos = kk * 32 + ((lf >> 4) << 3) + j;
    int ktrue = (kpos & ~31) | ((kpos >> 1) & 15) | ((kpos & 1) << 4);
    W2F[i] = f2bf_rne(W2[n * 128 + ktrue]);
    float v = (kpos < 64) ? W1[n * 256 + kpos]
                          : W1[n * 256 + 128 + (kpos - 64)] + W1[n * 256 + 192 + (kpos - 64)];
    WCF[i] = f2bf_rne(v);
    if (kk < 2) WBF[i] = f2bf_rne(W1[n * 256 + 64 + kpos]);   // K=64: h1-half only
}

// ---------- node-side: MFMA, register weight frags, direct coalesced stores ----------
__global__ __launch_bounds__(256, 4) void node_kernel(
    const float* __restrict__ h1, const float* __restrict__ h2,
    const ushort* __restrict__ WCF, const ushort* __restrict__ WBF,
    const float* __restrict__ b1,
    uint32_t* __restrict__ Aout, uint32_t* __restrict__ Bout, int N)
{
    __shared__ __align__(16) ushort xt[64 * 136];   // [node][k true order]
    const int tid = threadIdx.x, g = tid >> 6, ln = tid & 63;
    const int nl = ln & 15, q = ln >> 4;
    const int n0 = blockIdx.x * 64;
    const bool full = (n0 + 64 <= N);

    // wave g owns n-cols [g*32, g*32+32): 12 weight frags -> 48 VGPRs
    bf16x8 fa[4][2], fb[2][2];
    #pragma unroll
    for (int kk = 0; kk < 4; ++kk)
        #pragma unroll
        for (int nt = 0; nt < 2; ++nt)
            fa[kk][nt] = *(const bf16x8*)(WCF + (((kk * 8 + g * 2 + nt) * 64 + ln) << 3));
    #pragma unroll
    for (int kk = 0; kk < 2; ++kk)
        #pragma unroll
        for (int nt = 0; nt < 2; ++nt)
            fb[kk][nt] = *(const bf16x8*)(WBF + (((kk * 8 + g * 2 + nt) * 64 + ln) << 3));
    const float b1c0 = b1[g * 32 + nl], b1c1 = b1[g * 32 + 16 + nl];

    // stage X = [h1|h2] as bf16 (true k order)
    #pragma unroll
    for (int i = 0; i < 8; ++i) {
        int local = i * 256 + tid;
        int node = local >> 5;
        int kq = (local & 31) * 4;
        float4 x = make_float4(0.f, 0.f, 0.f, 0.f);
        if (full || n0 + node < N)
            x = (kq < 64) ? *(const float4*)(h1 + (size_t)(n0 + node) * 64 + kq)
                          : *(const float4*)(h2 + (size_t)(n0 + node) * 64 + (kq - 64));
        uint32_t d0 = packbf_rhu(x.x, x.y), d1 = packbf_rhu(x.z, x.w);
        *(uint2*)&xt[node * 136 + kq] = make_uint2(d0, d1);
    }
    __syncthreads();

    #pragma unroll
    for (int m = 0; m < 4; ++m) {
        f32x4 accA[2], accB[2];
        #pragma unroll
        for (int r = 0; r < 4; ++r) { accA[0][r] = accA[1][r] = accB[0][r] = accB[1][r] = 0.f; }
        const ushort* arow = &xt[(m * 16 + nl) * 136 + (q << 3)];
        #pragma unroll
        for (int kk = 0; kk < 4; ++kk) {
            bf16x8 a = *(const bf16x8*)(arow + kk * 32);
            accA[0] = __builtin_amdgcn_mfma_f32_16x16x32_bf16(a, fa[kk][0], accA[0], 0, 0, 0);
            accA[1] = __builtin_amdgcn_mfma_f32_16x16x32_bf16(a, fa[kk][1], accA[1], 0, 0, 0);
            if (kk < 2) {
                accB[0] = __builtin_amdgcn_mfma_f32_16x16x32_bf16(a, fb[kk][0], accB[0], 0, 0, 0);
                accB[1] = __builtin_amdgcn_mfma_f32_16x16x32_bf16(a, fb[kk][1], accB[1], 0, 0, 0);
            }
        }
        // C/D: node = m*16 + q*4 + r, cols (g*32+nl, +16) -> dword slot g*16+nl
        #pragma unroll
        for (int r = 0; r < 4; ++r) {
            int node = n0 + m * 16 + q * 4 + r;
            if (full || node < N) {
                Aout[(size_t)node * 64 + g * 16 + nl] = packbf_rhu(accA[0][r] + b1c0, accA[1][r] + b1c1);
                Bout[(size_t)node * 64 + g * 16 + nl] = packbf_rhu(accB[0][r], accB[1][r]);
            }
        }
    }
}

// ---------- edge-side: barrier-free loop, W2F in LDS, per-wave-independent ----------
// Wave handles edges [t*64+g*16, +16) for ALL 128 n-cols.
// Gather layout: lane ln -> edge el=ln>>2, 16B-quad p=ln&3; ga/gb[r] covers
//   dwords d = r*16 + p*4 + j of the edge's 64-dword row.
// A-frag: lane (q,nl) <- dwords kk*16+q*4+j of edge nl = source lane nl*4+q,
//   commit reg (kk,j) -> fused ds_bpermute right after each dword's sigmoid+pack.
__global__ __launch_bounds__(256, 4) void edge_kernel(
    const uint32_t* __restrict__ Am, const uint32_t* __restrict__ Bm,
    const int* __restrict__ src, const int* __restrict__ dst,
    const ushort* __restrict__ W2F, const float* __restrict__ b2,
    const float* __restrict__ W3, const float* __restrict__ b3,
    float* __restrict__ out, int E, int ntiles)
{
    __shared__ __align__(16) ushort w2lds[16384];   // 32 KB: full W2F frag table
    const int tid = threadIdx.x, g = tid >> 6, ln = tid & 63;
    const int nl = ln & 15, q = ln >> 4;
    const int el = ln >> 2;              // edge-local 0..15 for this lane's quad
    const int p  = ln & 3;               // 16B-quad within row
    const int G  = gridDim.x;
    const int sl = ((nl << 2) | q) << 2; // bpermute byte-addr: source lane nl*4+q

    // one-time cooperative W2F -> LDS (shared by all waves; frees 128 VGPRs)
    {
        const uint4* s = (const uint4*)W2F;
        uint4* d = (uint4*)w2lds;
        #pragma unroll
        for (int i = 0; i < 8; ++i) d[i * 256 + tid] = s[i * 256 + tid];
    }
    float b2c[8], w3c[8];
    #pragma unroll
    for (int nt = 0; nt < 8; ++nt) {
        int n = nt * 16 + nl;
        b2c[nt] = b2[n]; w3c[nt] = W3[n];
    }
    const float b3c = b3[0];
    __syncthreads();                     // w2lds ready; loop below is barrier-free

    uint4 ga[4], gb[4];
    int uB = 0, vB = 0;                  // indices for tile t+G (gathered next iter)
    int t = blockIdx.x;
    if (t < ntiles) {
        int e0 = t * 64 + g * 16 + el;
        int u0 = 0, v0 = 0;
        if (e0 < E) { u0 = src[e0]; v0 = dst[e0]; }
        const uint32_t* ap = Am + (size_t)u0 * 64 + p * 4;
        const uint32_t* bp = Bm + (size_t)v0 * 64 + p * 4;
        #pragma unroll
        for (int r = 0; r < 4; ++r) {
            ga[r] = *(const uint4*)(ap + r * 16);
            gb[r] = *(const uint4*)(bp + r * 16);
        }
        int t1 = t + G;
        if (t1 < ntiles) {
            int e1 = t1 * 64 + g * 16 + el;
            if (e1 < E) { uB = src[e1]; vB = dst[e1]; }
        }
    }
    for (; t < ntiles; t += G) {
        // ---- commit: sigmoid + pack + fused bpermute transpose ----
        i32x4 pa[4];
        #pragma unroll
        for (int r = 0; r < 4; ++r) {
            uint32_t sa[4] = {ga[r].x, ga[r].y, ga[r].z, ga[r].w};
            uint32_t sb[4] = {gb[r].x, gb[r].y, gb[r].z, gb[r].w};
            #pragma unroll
            for (int d = 0; d < 4; ++d) {
                float zl = bf2f_lo(sa[d]) + bf2f_lo(sb[d]);
                float zh = bf2f_hi(sa[d]) + bf2f_hi(sb[d]);
                int v = (int)packbf_rhu(sigmoid_fast(zl), sigmoid_fast(zh));
                pa[r][d] = __builtin_amdgcn_ds_bpermute(sl, v);
            }
        }
        // ---- issue idx loads for t+2G ----
        int uC = 0, vC = 0;
        int t2 = t + 2 * G;
        if (t2 < ntiles) {
            int e2 = t2 * 64 + g * 16 + el;
            if (e2 < E) { uC = src[e2]; vC = dst[e2]; }
        }
        // ---- issue gathers for t+G (covered by the whole MFMA+epilogue phase) ----
        if (t + G < ntiles) {
            const uint32_t* ap = Am + (size_t)uB * 64 + p * 4;
            const uint32_t* bp = Bm + (size_t)vB * 64 + p * 4;
            #pragma unroll
            for (int r = 0; r < 4; ++r) {
                ga[r] = *(const uint4*)(ap + r * 16);
                gb[r] = *(const uint4*)(bp + r * 16);
            }
        }
        // ---- MFMA per n-tile (B-frags from LDS) + fused layer3 epilogue ----
        float pr[4] = {0.f, 0.f, 0.f, 0.f};
        #pragma unroll
        for (int nt = 0; nt < 8; ++nt) {
            f32x4 acc = {0.f, 0.f, 0.f, 0.f};
            #pragma unroll
            for (int kk = 0; kk < 4; ++kk) {
                bf16x8 b = *(const bf16x8*)(w2lds + (((kk * 8 + nt) * 64 + ln) << 3));
                acc = __builtin_amdgcn_mfma_f32_16x16x32_bf16(
                    __builtin_bit_cast(bf16x8, pa[kk]), b, acc, 0, 0, 0);
            }
            #pragma unroll
            for (int r = 0; r < 4; ++r)
                pr[r] = fmaf(w3c[nt], sigmoid_fast(acc[r] + b2c[nt]), pr[r]);
        }
        // reduce over the 16 n-lanes (cols); D-row = edge q*4+r
        #pragma unroll
        for (int r = 0; r < 4; ++r) {
            pr[r] += __shfl_xor(pr[r], 1, 16);
            pr[r] += __shfl_xor(pr[r], 2, 16);
            pr[r] += __shfl_xor(pr[r], 4, 16);
            pr[r] += __shfl_xor(pr[r], 8, 16);
        }
        if (nl == 0) {
            int e0 = t * 64 + g * 16 + q * 4;
            if (e0 + 4 <= E) {
                f32x4 v = {pr[0] + b3c, pr[1] + b3c, pr[2] + b3c, pr[3] + b3c};
                *(f32x4*)(out + e0) = v;
            } else {
                #pragma unroll
                for (int r = 0; r < 4; ++r)
                    if (e0 + r < E) out[e0 + r] = pr[r] + b3c;
            }
        }
        uB = uC; vB = vC;
    }
}

// ---------- fallback (only if workspace too small) ----------
__global__ void naive_kernel(
    const float* __restrict__ h1, const float* __restrict__ h2,
    const int* __restrict__ src, const int* __restrict__ dst,
    const float* __restrict__ W1, const float* __restrict__ b1,
    const float* __restrict__ W2, const float* __restrict__ b2,
    const float* __restrict__ W3, const float* __restrict__ b3,
    float* __restrict__ out, int E, int N)
{
    int e = blockIdx.x * blockDim.x + threadIdx.x;
    if (e >= E) return;
    int u = src[e], v = dst[e];
    float h[128];
    for (int j = 0; j < 128; ++j) {
        float z = b1[j];
        const float* wj = W1 + j * 256;
        for (int k = 0; k < 64; ++k) {
            z += wj[k] * h1[(size_t)u * 64 + k]
               + wj[64 + k] * h1[(size_t)v * 64 + k]
               + (wj[128 + k] + wj[192 + k]) * h2[(size_t)u * 64 + k];
        }
        h[j] = 1.0f / (1.0f + __expf(-z));
    }
    float gg[128];
    for (int j = 0; j < 128; ++j) {
        float z = b2[j];
        for (int k = 0; k < 128; ++k) z = fmaf(W2[j * 128 + k], h[k], z);
        gg[j] = 1.0f / (1.0f + __expf(-z));
    }
    float s = b3[0];
    for (int j = 0; j < 128; ++j) s = fmaf(W3[j], gg[j], s);
    out[e] = s;
}

extern "C" void kernel_launch(void* const* d_in, const int* in_sizes, int n_in,
                              void* d_out, int out_size, void* d_ws, size_t ws_size,
                              hipStream_t stream) {
    const float* h1 = (const float*)d_in[0];
    const float* h2 = (const float*)d_in[1];
    const int*  src = (const int*)d_in[2];
    const int*  dst = (const int*)d_in[3];
    const float* W1 = (const float*)d_in[4];
    const float* b1 = (const float*)d_in[5];
    const float* W2 = (const float*)d_in[6];
    const float* b2 = (const float*)d_in[7];
    const float* W3 = (const float*)d_in[8];
    const float* b3 = (const float*)d_in[9];
    float* out = (float*)d_out;

    const int N = in_sizes[0] / 64;
    const int E = in_sizes[2];

    // workspace layout (float units)
    size_t offA   = 0;                         // N*64 dwords (bf16-pair packed)
    size_t offB   = offA + (size_t)N * 64;
    size_t offWCF = offB + (size_t)N * 64;     // 16384 ushorts
    size_t offWBF = offWCF + 8192;             // 8192 ushorts
    size_t offW2F = offWBF + 4096;             // 16384 ushorts
    size_t totalF = offW2F + 8192;

    if (ws_size < totalF * sizeof(float)) {
        naive_kernel<<<(E + 255) / 256, 256, 0, stream>>>(
            h1, h2, src, dst, W1, b1, W2, b2, W3, b3, out, E, N);
        return;
    }

    float* ws = (float*)d_ws;
    ushort* WCF = (ushort*)(ws + offWCF);
    ushort* WBF = (ushort*)(ws + offWBF);
    ushort* W2F = (ushort*)(ws + offW2F);

    prep_kernel<<<64, 256, 0, stream>>>(W1, W2, WCF, WBF, W2F);
    node_kernel<<<(N + 63) / 64, 256, 0, stream>>>(
        h1, h2, WCF, WBF, b1, (uint32_t*)(ws + offA), (uint32_t*)(ws + offB), N);
    const int ntiles = (E + 63) / 64;
    const int nblk = ntiles < 1024 ? ntiles : 1024;   // 4 blocks/CU (32KB LDS, 4 w/SIMD)
    edge_kernel<<<nblk, 256, 0, stream>>>(
        (const uint32_t*)(ws + offA), (const uint32_t*)(ws + offB), src, dst,
        W2F, b2, W3, b3, out, E, ntiles);
}

// Round 7
// 183.371 us; speedup vs baseline: 1.1997x; 1.1997x over previous
//
#include <hip/hip_runtime.h>
#include <hip/hip_bf16.h>
#include <cstdint>

// EdgeMLP: score = W3 @ sig(W2 @ sig(W1 @ [h1_u,h1_v,h2_u,h2_u] + b1) + b2) + b3
// Factored: z1 = Anode[src] + Bnode[dst]  (A/B stored bf16, PERMUTED col order:
//   dword slot d of a row holds true cols (32*(d>>4) + (d&15), +16) as (lo,hi);
//   compensated in W2F's k-index in prep).
// R14: R13 (W2F in LDS, barrier-free loop, fused bpermute) spilled at the
//   (256,4)=128-VGPR cap: true demand ~140 (ga/gb 32 + pa 16 + b2c/w3c 16 +
//   in-flight LDS b-frags + addressing) -> 500MB scratch traffic, 130 µs.
//   SINGLE CHANGE: __launch_bounds__(256,3) -> 168-VGPR cap (> demand, no
//   spill), 3 waves/SIMD (vs R12's 2), grid 768 (3 blocks/CU, 96KB LDS).
//   Tripwire: WRITE_SIZE ballooning again => revert to R12 next round.

typedef __attribute__((ext_vector_type(8))) short bf16x8;
typedef __attribute__((ext_vector_type(4))) float f32x4;
typedef __attribute__((ext_vector_type(4))) int   i32x4;

__device__ __forceinline__ float sigmoid_fast(float x) {
    float e = __expf(-x);                       // v_mul + v_exp
    return __builtin_amdgcn_rcpf(1.0f + e);     // v_add + v_rcp  (~1 ulp)
}
__device__ __forceinline__ ushort f2bf_rne(float f) {      // prep path only
    uint32_t u = __float_as_uint(f);
    return (ushort)((u + 0x7fffu + ((u >> 16) & 1u)) >> 16);
}
__device__ __forceinline__ float bf2f_lo(uint32_t d) { return __uint_as_float(d << 16); }
__device__ __forceinline__ float bf2f_hi(uint32_t d) { return __uint_as_float(d & 0xffff0000u); }
__device__ __forceinline__ uint32_t packbf_rhu(float x, float y) {   // round-half-up
    return ((__float_as_uint(x) + 0x8000u) >> 16) |
           ((__float_as_uint(y) + 0x8000u) & 0xffff0000u);
}

// ---------- prep: weights -> bf16 MFMA B-fragment layouts ----------
// frag idx: ((kk*8+nt)*64+lane)*8 + j ; n = nt*16+(lane&15) ; kpos = kk*32+(lane>>4)*8+j
// WCF/WBF use true k = kpos. W2F uses permuted ktrue to match A/B dword packing.
__global__ void prep_kernel(const float* __restrict__ W1, const float* __restrict__ W2,
                            ushort* __restrict__ WCF, ushort* __restrict__ WBF,
                            ushort* __restrict__ W2F) {
    int i = blockIdx.x * blockDim.x + threadIdx.x;
    if (i >= 16384) return;
    int j = i & 7, lf = (i >> 3) & 63, nt = (i >> 9) & 7, kk = i >> 12;
    int n = nt * 16 + (lf & 15);
    int kpos = kk * 32 + ((lf >> 4) << 3) + j;
    int ktrue = (kpos & ~31) | ((kpos >> 1) & 15) | ((kpos & 1) << 4);
    W2F[i] = f2bf_rne(W2[n * 128 + ktrue]);
    float v = (kpos < 64) ? W1[n * 256 + kpos]
                          : W1[n * 256 + 128 + (kpos - 64)] + W1[n * 256 + 192 + (kpos - 64)];
    WCF[i] = f2bf_rne(v);
    if (kk < 2) WBF[i] = f2bf_rne(W1[n * 256 + 64 + kpos]);   // K=64: h1-half only
}

// ---------- node-side: MFMA, register weight frags, direct coalesced stores ----------
__global__ __launch_bounds__(256, 4) void node_kernel(
    const float* __restrict__ h1, const float* __restrict__ h2,
    const ushort* __restrict__ WCF, const ushort* __restrict__ WBF,
    const float* __restrict__ b1,
    uint32_t* __restrict__ Aout, uint32_t* __restrict__ Bout, int N)
{
    __shared__ __align__(16) ushort xt[64 * 136];   // [node][k true order]
    const int tid = threadIdx.x, g = tid >> 6, ln = tid & 63;
    const int nl = ln & 15, q = ln >> 4;
    const int n0 = blockIdx.x * 64;
    const bool full = (n0 + 64 <= N);

    // wave g owns n-cols [g*32, g*32+32): 12 weight frags -> 48 VGPRs
    bf16x8 fa[4][2], fb[2][2];
    #pragma unroll
    for (int kk = 0; kk < 4; ++kk)
        #pragma unroll
        for (int nt = 0; nt < 2; ++nt)
            fa[kk][nt] = *(const bf16x8*)(WCF + (((kk * 8 + g * 2 + nt) * 64 + ln) << 3));
    #pragma unroll
    for (int kk = 0; kk < 2; ++kk)
        #pragma unroll
        for (int nt = 0; nt < 2; ++nt)
            fb[kk][nt] = *(const bf16x8*)(WBF + (((kk * 8 + g * 2 + nt) * 64 + ln) << 3));
    const float b1c0 = b1[g * 32 + nl], b1c1 = b1[g * 32 + 16 + nl];

    // stage X = [h1|h2] as bf16 (true k order)
    #pragma unroll
    for (int i = 0; i < 8; ++i) {
        int local = i * 256 + tid;
        int node = local >> 5;
        int kq = (local & 31) * 4;
        float4 x = make_float4(0.f, 0.f, 0.f, 0.f);
        if (full || n0 + node < N)
            x = (kq < 64) ? *(const float4*)(h1 + (size_t)(n0 + node) * 64 + kq)
                          : *(const float4*)(h2 + (size_t)(n0 + node) * 64 + (kq - 64));
        uint32_t d0 = packbf_rhu(x.x, x.y), d1 = packbf_rhu(x.z, x.w);
        *(uint2*)&xt[node * 136 + kq] = make_uint2(d0, d1);
    }
    __syncthreads();

    #pragma unroll
    for (int m = 0; m < 4; ++m) {
        f32x4 accA[2], accB[2];
        #pragma unroll
        for (int r = 0; r < 4; ++r) { accA[0][r] = accA[1][r] = accB[0][r] = accB[1][r] = 0.f; }
        const ushort* arow = &xt[(m * 16 + nl) * 136 + (q << 3)];
        #pragma unroll
        for (int kk = 0; kk < 4; ++kk) {
            bf16x8 a = *(const bf16x8*)(arow + kk * 32);
            accA[0] = __builtin_amdgcn_mfma_f32_16x16x32_bf16(a, fa[kk][0], accA[0], 0, 0, 0);
            accA[1] = __builtin_amdgcn_mfma_f32_16x16x32_bf16(a, fa[kk][1], accA[1], 0, 0, 0);
            if (kk < 2) {
                accB[0] = __builtin_amdgcn_mfma_f32_16x16x32_bf16(a, fb[kk][0], accB[0], 0, 0, 0);
                accB[1] = __builtin_amdgcn_mfma_f32_16x16x32_bf16(a, fb[kk][1], accB[1], 0, 0, 0);
            }
        }
        // C/D: node = m*16 + q*4 + r, cols (g*32+nl, +16) -> dword slot g*16+nl
        #pragma unroll
        for (int r = 0; r < 4; ++r) {
            int node = n0 + m * 16 + q * 4 + r;
            if (full || node < N) {
                Aout[(size_t)node * 64 + g * 16 + nl] = packbf_rhu(accA[0][r] + b1c0, accA[1][r] + b1c1);
                Bout[(size_t)node * 64 + g * 16 + nl] = packbf_rhu(accB[0][r], accB[1][r]);
            }
        }
    }
}

// ---------- edge-side: barrier-free loop, W2F in LDS, per-wave-independent ----------
// Wave handles edges [t*64+g*16, +16) for ALL 128 n-cols.
// Gather layout: lane ln -> edge el=ln>>2, 16B-quad p=ln&3; ga/gb[r] covers
//   dwords d = r*16 + p*4 + j of the edge's 64-dword row.
// A-frag: lane (q,nl) <- dwords kk*16+q*4+j of edge nl = source lane nl*4+q,
//   commit reg (kk,j) -> fused ds_bpermute right after each dword's sigmoid+pack.
__global__ __launch_bounds__(256, 3) void edge_kernel(
    const uint32_t* __restrict__ Am, const uint32_t* __restrict__ Bm,
    const int* __restrict__ src, const int* __restrict__ dst,
    const ushort* __restrict__ W2F, const float* __restrict__ b2,
    const float* __restrict__ W3, const float* __restrict__ b3,
    float* __restrict__ out, int E, int ntiles)
{
    __shared__ __align__(16) ushort w2lds[16384];   // 32 KB: full W2F frag table
    const int tid = threadIdx.x, g = tid >> 6, ln = tid & 63;
    const int nl = ln & 15, q = ln >> 4;
    const int el = ln >> 2;              // edge-local 0..15 for this lane's quad
    const int p  = ln & 3;               // 16B-quad within row
    const int G  = gridDim.x;
    const int sl = ((nl << 2) | q) << 2; // bpermute byte-addr: source lane nl*4+q

    // one-time cooperative W2F -> LDS (shared by all waves; frees 128 VGPRs)
    {
        const uint4* s = (const uint4*)W2F;
        uint4* d = (uint4*)w2lds;
        #pragma unroll
        for (int i = 0; i < 8; ++i) d[i * 256 + tid] = s[i * 256 + tid];
    }
    float b2c[8], w3c[8];
    #pragma unroll
    for (int nt = 0; nt < 8; ++nt) {
        int n = nt * 16 + nl;
        b2c[nt] = b2[n]; w3c[nt] = W3[n];
    }
    const float b3c = b3[0];
    __syncthreads();                     // w2lds ready; loop below is barrier-free

    uint4 ga[4], gb[4];
    int uB = 0, vB = 0;                  // indices for tile t+G (gathered next iter)
    int t = blockIdx.x;
    if (t < ntiles) {
        int e0 = t * 64 + g * 16 + el;
        int u0 = 0, v0 = 0;
        if (e0 < E) { u0 = src[e0]; v0 = dst[e0]; }
        const uint32_t* ap = Am + (size_t)u0 * 64 + p * 4;
        const uint32_t* bp = Bm + (size_t)v0 * 64 + p * 4;
        #pragma unroll
        for (int r = 0; r < 4; ++r) {
            ga[r] = *(const uint4*)(ap + r * 16);
            gb[r] = *(const uint4*)(bp + r * 16);
        }
        int t1 = t + G;
        if (t1 < ntiles) {
            int e1 = t1 * 64 + g * 16 + el;
            if (e1 < E) { uB = src[e1]; vB = dst[e1]; }
        }
    }
    for (; t < ntiles; t += G) {
        // ---- commit: sigmoid + pack + fused bpermute transpose ----
        i32x4 pa[4];
        #pragma unroll
        for (int r = 0; r < 4; ++r) {
            uint32_t sa[4] = {ga[r].x, ga[r].y, ga[r].z, ga[r].w};
            uint32_t sb[4] = {gb[r].x, gb[r].y, gb[r].z, gb[r].w};
            #pragma unroll
            for (int d = 0; d < 4; ++d) {
                float zl = bf2f_lo(sa[d]) + bf2f_lo(sb[d]);
                float zh = bf2f_hi(sa[d]) + bf2f_hi(sb[d]);
                int v = (int)packbf_rhu(sigmoid_fast(zl), sigmoid_fast(zh));
                pa[r][d] = __builtin_amdgcn_ds_bpermute(sl, v);
            }
        }
        // ---- issue idx loads for t+2G ----
        int uC = 0, vC = 0;
        int t2 = t + 2 * G;
        if (t2 < ntiles) {
            int e2 = t2 * 64 + g * 16 + el;
            if (e2 < E) { uC = src[e2]; vC = dst[e2]; }
        }
        // ---- issue gathers for t+G (covered by the whole MFMA+epilogue phase) ----
        if (t + G < ntiles) {
            const uint32_t* ap = Am + (size_t)uB * 64 + p * 4;
            const uint32_t* bp = Bm + (size_t)vB * 64 + p * 4;
            #pragma unroll
            for (int r = 0; r < 4; ++r) {
                ga[r] = *(const uint4*)(ap + r * 16);
                gb[r] = *(const uint4*)(bp + r * 16);
            }
        }
        // ---- MFMA per n-tile (B-frags from LDS) + fused layer3 epilogue ----
        float pr[4] = {0.f, 0.f, 0.f, 0.f};
        #pragma unroll
        for (int nt = 0; nt < 8; ++nt) {
            f32x4 acc = {0.f, 0.f, 0.f, 0.f};
            #pragma unroll
            for (int kk = 0; kk < 4; ++kk) {
                bf16x8 b = *(const bf16x8*)(w2lds + (((kk * 8 + nt) * 64 + ln) << 3));
                acc = __builtin_amdgcn_mfma_f32_16x16x32_bf16(
                    __builtin_bit_cast(bf16x8, pa[kk]), b, acc, 0, 0, 0);
            }
            #pragma unroll
            for (int r = 0; r < 4; ++r)
                pr[r] = fmaf(w3c[nt], sigmoid_fast(acc[r] + b2c[nt]), pr[r]);
        }
        // reduce over the 16 n-lanes (cols); D-row = edge q*4+r
        #pragma unroll
        for (int r = 0; r < 4; ++r) {
            pr[r] += __shfl_xor(pr[r], 1, 16);
            pr[r] += __shfl_xor(pr[r], 2, 16);
            pr[r] += __shfl_xor(pr[r], 4, 16);
            pr[r] += __shfl_xor(pr[r], 8, 16);
        }
        if (nl == 0) {
            int e0 = t * 64 + g * 16 + q * 4;
            if (e0 + 4 <= E) {
                f32x4 v = {pr[0] + b3c, pr[1] + b3c, pr[2] + b3c, pr[3] + b3c};
                *(f32x4*)(out + e0) = v;
            } else {
                #pragma unroll
                for (int r = 0; r < 4; ++r)
                    if (e0 + r < E) out[e0 + r] = pr[r] + b3c;
            }
        }
        uB = uC; vB = vC;
    }
}

// ---------- fallback (only if workspace too small) ----------
__global__ void naive_kernel(
    const float* __restrict__ h1, const float* __restrict__ h2,
    const int* __restrict__ src, const int* __restrict__ dst,
    const float* __restrict__ W1, const float* __restrict__ b1,
    const float* __restrict__ W2, const float* __restrict__ b2,
    const float* __restrict__ W3, const float* __restrict__ b3,
    float* __restrict__ out, int E, int N)
{
    int e = blockIdx.x * blockDim.x + threadIdx.x;
    if (e >= E) return;
    int u = src[e], v = dst[e];
    float h[128];
    for (int j = 0; j < 128; ++j) {
        float z = b1[j];
        const float* wj = W1 + j * 256;
        for (int k = 0; k < 64; ++k) {
            z += wj[k] * h1[(size_t)u * 64 + k]
               + wj[64 + k] * h1[(size_t)v * 64 + k]
               + (wj[128 + k] + wj[192 + k]) * h2[(size_t)u * 64 + k];
        }
        h[j] = 1.0f / (1.0f + __expf(-z));
    }
    float gg[128];
    for (int j = 0; j < 128; ++j) {
        float z = b2[j];
        for (int k = 0; k < 128; ++k) z = fmaf(W2[j * 128 + k], h[k], z);
        gg[j] = 1.0f / (1.0f + __expf(-z));
    }
    float s = b3[0];
    for (int j = 0; j < 128; ++j) s = fmaf(W3[j], gg[j], s);
    out[e] = s;
}

extern "C" void kernel_launch(void* const* d_in, const int* in_sizes, int n_in,
                              void* d_out, int out_size, void* d_ws, size_t ws_size,
                              hipStream_t stream) {
    const float* h1 = (const float*)d_in[0];
    const float* h2 = (const float*)d_in[1];
    const int*  src = (const int*)d_in[2];
    const int*  dst = (const int*)d_in[3];
    const float* W1 = (const float*)d_in[4];
    const float* b1 = (const float*)d_in[5];
    const float* W2 = (const float*)d_in[6];
    const float* b2 = (const float*)d_in[7];
    const float* W3 = (const float*)d_in[8];
    const float* b3 = (const float*)d_in[9];
    float* out = (float*)d_out;

    const int N = in_sizes[0] / 64;
    const int E = in_sizes[2];

    // workspace layout (float units)
    size_t offA   = 0;                         // N*64 dwords (bf16-pair packed)
    size_t offB   = offA + (size_t)N * 64;
    size_t offWCF = offB + (size_t)N * 64;     // 16384 ushorts
    size_t offWBF = offWCF + 8192;             // 8192 ushorts
    size_t offW2F = offWBF + 4096;             // 16384 ushorts
    size_t totalF = offW2F + 8192;

    if (ws_size < totalF * sizeof(float)) {
        naive_kernel<<<(E + 255) / 256, 256, 0, stream>>>(
            h1, h2, src, dst, W1, b1, W2, b2, W3, b3, out, E, N);
        return;
    }

    float* ws = (float*)d_ws;
    ushort* WCF = (ushort*)(ws + offWCF);
    ushort* WBF = (ushort*)(ws + offWBF);
    ushort* W2F = (ushort*)(ws + offW2F);

    prep_kernel<<<64, 256, 0, stream>>>(W1, W2, WCF, WBF, W2F);
    node_kernel<<<(N + 63) / 64, 256, 0, stream>>>(
        h1, h2, WCF, WBF, b1, (uint32_t*)(ws + offA), (uint32_t*)(ws + offB), N);
    const int ntiles = (E + 63) / 64;
    const int nblk = ntiles < 768 ? ntiles : 768;   // 3 blocks/CU (96KB LDS, 3 w/SIMD)
    edge_kernel<<<nblk, 256, 0, stream>>>(
        (const uint32_t*)(ws + offA), (const uint32_t*)(ws + offB), src, dst,
        W2F, b2, W3, b3, out, E, ntiles);
}

// Round 8
// 131.892 us; speedup vs baseline: 1.6680x; 1.3903x over previous
//
#include <hip/hip_runtime.h>
#include <hip/hip_bf16.h>
#include <cstdint>

// EdgeMLP: score = W3 @ sig(W2 @ sig(W1 @ [h1_u,h1_v,h2_u,h2_u] + b1) + b2) + b3
// Factored: z1 = Anode[src] + Bnode[dst]  (A/B stored bf16, PERMUTED col order;
//   compensated in W2F's k-index in prep).
// R15: R13/R14 spills diagnosed — the fully-unrolled nt loop makes hipcc hoist
//   all 32 ds_read_b128 B-frags (128 transient VGPRs); under any cap <210 it
//   spills ga/gb. Fix: RUNTIME nt loop (unroll(disable)) so only one nt's
//   4 B-frags are in flight; b2/W3 go to a small LDS table (bwlds) to avoid
//   rule-#20 runtime-indexed register arrays. Live set ~100 -> (256,4) with
//   NO spills, 4 waves/SIMD, barrier-free loop. First variant combining
//   barrier-free + 4 w/SIMD + spill-free.
//   Tripwire: WRITE_SIZE ballooning again => revert to R12 (best, 130.55).

typedef __attribute__((ext_vector_type(8))) short bf16x8;
typedef __attribute__((ext_vector_type(4))) float f32x4;
typedef __attribute__((ext_vector_type(4))) int   i32x4;

__device__ __forceinline__ float sigmoid_fast(float x) {
    float e = __expf(-x);                       // v_mul + v_exp
    return __builtin_amdgcn_rcpf(1.0f + e);     // v_add + v_rcp  (~1 ulp)
}
__device__ __forceinline__ ushort f2bf_rne(float f) {      // prep path only
    uint32_t u = __float_as_uint(f);
    return (ushort)((u + 0x7fffu + ((u >> 16) & 1u)) >> 16);
}
__device__ __forceinline__ float bf2f_lo(uint32_t d) { return __uint_as_float(d << 16); }
__device__ __forceinline__ float bf2f_hi(uint32_t d) { return __uint_as_float(d & 0xffff0000u); }
__device__ __forceinline__ uint32_t packbf_rhu(float x, float y) {   // round-half-up
    return ((__float_as_uint(x) + 0x8000u) >> 16) |
           ((__float_as_uint(y) + 0x8000u) & 0xffff0000u);
}

// ---------- prep: weights -> bf16 MFMA B-fragment layouts ----------
// frag idx: ((kk*8+nt)*64+lane)*8 + j ; n = nt*16+(lane&15) ; kpos = kk*32+(lane>>4)*8+j
// WCF/WBF use true k = kpos. W2F uses permuted ktrue to match A/B dword packing.
__global__ void prep_kernel(const float* __restrict__ W1, const float* __restrict__ W2,
                            ushort* __restrict__ WCF, ushort* __restrict__ WBF,
                            ushort* __restrict__ W2F) {
    int i = blockIdx.x * blockDim.x + threadIdx.x;
    if (i >= 16384) return;
    int j = i & 7, lf = (i >> 3) & 63, nt = (i >> 9) & 7, kk = i >> 12;
    int n = nt * 16 + (lf & 15);
    int kpos = kk * 32 + ((lf >> 4) << 3) + j;
    int ktrue = (kpos & ~31) | ((kpos >> 1) & 15) | ((kpos & 1) << 4);
    W2F[i] = f2bf_rne(W2[n * 128 + ktrue]);
    float v = (kpos < 64) ? W1[n * 256 + kpos]
                          : W1[n * 256 + 128 + (kpos - 64)] + W1[n * 256 + 192 + (kpos - 64)];
    WCF[i] = f2bf_rne(v);
    if (kk < 2) WBF[i] = f2bf_rne(W1[n * 256 + 64 + kpos]);   // K=64: h1-half only
}

// ---------- node-side: MFMA, register weight frags, direct coalesced stores ----------
__global__ __launch_bounds__(256, 4) void node_kernel(
    const float* __restrict__ h1, const float* __restrict__ h2,
    const ushort* __restrict__ WCF, const ushort* __restrict__ WBF,
    const float* __restrict__ b1,
    uint32_t* __restrict__ Aout, uint32_t* __restrict__ Bout, int N)
{
    __shared__ __align__(16) ushort xt[64 * 136];   // [node][k true order]
    const int tid = threadIdx.x, g = tid >> 6, ln = tid & 63;
    const int nl = ln & 15, q = ln >> 4;
    const int n0 = blockIdx.x * 64;
    const bool full = (n0 + 64 <= N);

    // wave g owns n-cols [g*32, g*32+32): 12 weight frags -> 48 VGPRs
    bf16x8 fa[4][2], fb[2][2];
    #pragma unroll
    for (int kk = 0; kk < 4; ++kk)
        #pragma unroll
        for (int nt = 0; nt < 2; ++nt)
            fa[kk][nt] = *(const bf16x8*)(WCF + (((kk * 8 + g * 2 + nt) * 64 + ln) << 3));
    #pragma unroll
    for (int kk = 0; kk < 2; ++kk)
        #pragma unroll
        for (int nt = 0; nt < 2; ++nt)
            fb[kk][nt] = *(const bf16x8*)(WBF + (((kk * 8 + g * 2 + nt) * 64 + ln) << 3));
    const float b1c0 = b1[g * 32 + nl], b1c1 = b1[g * 32 + 16 + nl];

    // stage X = [h1|h2] as bf16 (true k order)
    #pragma unroll
    for (int i = 0; i < 8; ++i) {
        int local = i * 256 + tid;
        int node = local >> 5;
        int kq = (local & 31) * 4;
        float4 x = make_float4(0.f, 0.f, 0.f, 0.f);
        if (full || n0 + node < N)
            x = (kq < 64) ? *(const float4*)(h1 + (size_t)(n0 + node) * 64 + kq)
                          : *(const float4*)(h2 + (size_t)(n0 + node) * 64 + (kq - 64));
        uint32_t d0 = packbf_rhu(x.x, x.y), d1 = packbf_rhu(x.z, x.w);
        *(uint2*)&xt[node * 136 + kq] = make_uint2(d0, d1);
    }
    __syncthreads();

    #pragma unroll
    for (int m = 0; m < 4; ++m) {
        f32x4 accA[2], accB[2];
        #pragma unroll
        for (int r = 0; r < 4; ++r) { accA[0][r] = accA[1][r] = accB[0][r] = accB[1][r] = 0.f; }
        const ushort* arow = &xt[(m * 16 + nl) * 136 + (q << 3)];
        #pragma unroll
        for (int kk = 0; kk < 4; ++kk) {
            bf16x8 a = *(const bf16x8*)(arow + kk * 32);
            accA[0] = __builtin_amdgcn_mfma_f32_16x16x32_bf16(a, fa[kk][0], accA[0], 0, 0, 0);
            accA[1] = __builtin_amdgcn_mfma_f32_16x16x32_bf16(a, fa[kk][1], accA[1], 0, 0, 0);
            if (kk < 2) {
                accB[0] = __builtin_amdgcn_mfma_f32_16x16x32_bf16(a, fb[kk][0], accB[0], 0, 0, 0);
                accB[1] = __builtin_amdgcn_mfma_f32_16x16x32_bf16(a, fb[kk][1], accB[1], 0, 0, 0);
            }
        }
        // C/D: node = m*16 + q*4 + r, cols (g*32+nl, +16) -> dword slot g*16+nl
        #pragma unroll
        for (int r = 0; r < 4; ++r) {
            int node = n0 + m * 16 + q * 4 + r;
            if (full || node < N) {
                Aout[(size_t)node * 64 + g * 16 + nl] = packbf_rhu(accA[0][r] + b1c0, accA[1][r] + b1c1);
                Bout[(size_t)node * 64 + g * 16 + nl] = packbf_rhu(accB[0][r], accB[1][r]);
            }
        }
    }
}

// ---------- edge-side: barrier-free loop, W2F in LDS, runtime nt loop ----------
// Wave handles edges [t*64+g*16, +16) for ALL 128 n-cols.
// Gather layout: lane ln -> edge el=ln>>2, 16B-quad p=ln&3; ga/gb[r] covers
//   dwords d = r*16 + p*4 + j of the edge's 64-dword row.
// A-frag: lane (q,nl) <- dwords kk*16+q*4+j of edge nl = source lane nl*4+q,
//   commit reg (kk,j) -> fused ds_bpermute right after each dword's sigmoid+pack.
// nt loop is a RUNTIME loop: caps in-flight B-frags at one nt (16 VGPRs),
//   keeping live set under the (256,4) 128-VGPR cap. b2/W3 come from bwlds
//   per-nt (no runtime-indexed register arrays -> no scratch).
__global__ __launch_bounds__(256, 4) void edge_kernel(
    const uint32_t* __restrict__ Am, const uint32_t* __restrict__ Bm,
    const int* __restrict__ src, const int* __restrict__ dst,
    const ushort* __restrict__ W2F, const float* __restrict__ b2,
    const float* __restrict__ W3, const float* __restrict__ b3,
    float* __restrict__ out, int E, int ntiles)
{
    __shared__ __align__(16) ushort w2lds[16384];   // 32 KB: full W2F frag table
    __shared__ __align__(8)  float2 bwlds[128];     // 1 KB: (b2[n], W3[n])
    const int tid = threadIdx.x, g = tid >> 6, ln = tid & 63;
    const int nl = ln & 15, q = ln >> 4;
    const int el = ln >> 2;              // edge-local 0..15 for this lane's quad
    const int p  = ln & 3;               // 16B-quad within row
    const int G  = gridDim.x;
    const int sl = ((nl << 2) | q) << 2; // bpermute byte-addr: source lane nl*4+q

    // one-time cooperative W2F + (b2,W3) -> LDS
    {
        const uint4* s = (const uint4*)W2F;
        uint4* d = (uint4*)w2lds;
        #pragma unroll
        for (int i = 0; i < 8; ++i) d[i * 256 + tid] = s[i * 256 + tid];
        if (tid < 128) bwlds[tid] = make_float2(b2[tid], W3[tid]);
    }
    const float b3c = b3[0];
    __syncthreads();                     // LDS ready; loop below is barrier-free

    uint4 ga[4], gb[4];
    int uB = 0, vB = 0;                  // indices for tile t+G (gathered next iter)
    int t = blockIdx.x;
    if (t < ntiles) {
        int e0 = t * 64 + g * 16 + el;
        int u0 = 0, v0 = 0;
        if (e0 < E) { u0 = src[e0]; v0 = dst[e0]; }
        const uint32_t* ap = Am + (size_t)u0 * 64 + p * 4;
        const uint32_t* bp = Bm + (size_t)v0 * 64 + p * 4;
        #pragma unroll
        for (int r = 0; r < 4; ++r) {
            ga[r] = *(const uint4*)(ap + r * 16);
            gb[r] = *(const uint4*)(bp + r * 16);
        }
        int t1 = t + G;
        if (t1 < ntiles) {
            int e1 = t1 * 64 + g * 16 + el;
            if (e1 < E) { uB = src[e1]; vB = dst[e1]; }
        }
    }
    for (; t < ntiles; t += G) {
        // ---- commit: sigmoid + pack + fused bpermute transpose ----
        i32x4 pa[4];
        #pragma unroll
        for (int r = 0; r < 4; ++r) {
            uint32_t sa[4] = {ga[r].x, ga[r].y, ga[r].z, ga[r].w};
            uint32_t sb[4] = {gb[r].x, gb[r].y, gb[r].z, gb[r].w};
            #pragma unroll
            for (int d = 0; d < 4; ++d) {
                float zl = bf2f_lo(sa[d]) + bf2f_lo(sb[d]);
                float zh = bf2f_hi(sa[d]) + bf2f_hi(sb[d]);
                int v = (int)packbf_rhu(sigmoid_fast(zl), sigmoid_fast(zh));
                pa[r][d] = __builtin_amdgcn_ds_bpermute(sl, v);
            }
        }
        // ---- issue idx loads for t+2G ----
        int uC = 0, vC = 0;
        int t2 = t + 2 * G;
        if (t2 < ntiles) {
            int e2 = t2 * 64 + g * 16 + el;
            if (e2 < E) { uC = src[e2]; vC = dst[e2]; }
        }
        // ---- issue gathers for t+G (covered by the MFMA+epilogue phase) ----
        if (t + G < ntiles) {
            const uint32_t* ap = Am + (size_t)uB * 64 + p * 4;
            const uint32_t* bp = Bm + (size_t)vB * 64 + p * 4;
            #pragma unroll
            for (int r = 0; r < 4; ++r) {
                ga[r] = *(const uint4*)(ap + r * 16);
                gb[r] = *(const uint4*)(bp + r * 16);
            }
        }
        // ---- MFMA per n-tile (B-frags from LDS) + fused layer3 epilogue ----
        // RUNTIME loop: limits live B-frags to one nt -> no spill under (256,4).
        float pr[4] = {0.f, 0.f, 0.f, 0.f};
        #pragma clang loop unroll(disable)
        for (int nt = 0; nt < 8; ++nt) {
            f32x4 acc = {0.f, 0.f, 0.f, 0.f};
            #pragma unroll
            for (int kk = 0; kk < 4; ++kk) {
                bf16x8 b = *(const bf16x8*)(w2lds + (((kk * 8 + nt) * 64 + ln) << 3));
                acc = __builtin_amdgcn_mfma_f32_16x16x32_bf16(
                    __builtin_bit_cast(bf16x8, pa[kk]), b, acc, 0, 0, 0);
            }
            float2 bw = bwlds[nt * 16 + nl];
            #pragma unroll
            for (int r = 0; r < 4; ++r)
                pr[r] = fmaf(bw.y, sigmoid_fast(acc[r] + bw.x), pr[r]);
        }
        // reduce over the 16 n-lanes (cols); D-row = edge q*4+r
        #pragma unroll
        for (int r = 0; r < 4; ++r) {
            pr[r] += __shfl_xor(pr[r], 1, 16);
            pr[r] += __shfl_xor(pr[r], 2, 16);
            pr[r] += __shfl_xor(pr[r], 4, 16);
            pr[r] += __shfl_xor(pr[r], 8, 16);
        }
        if (nl == 0) {
            int e0 = t * 64 + g * 16 + q * 4;
            if (e0 + 4 <= E) {
                f32x4 v = {pr[0] + b3c, pr[1] + b3c, pr[2] + b3c, pr[3] + b3c};
                *(f32x4*)(out + e0) = v;
            } else {
                #pragma unroll
                for (int r = 0; r < 4; ++r)
                    if (e0 + r < E) out[e0 + r] = pr[r] + b3c;
            }
        }
        uB = uC; vB = vC;
    }
}

// ---------- fallback (only if workspace too small) ----------
__global__ void naive_kernel(
    const float* __restrict__ h1, const float* __restrict__ h2,
    const int* __restrict__ src, const int* __restrict__ dst,
    const float* __restrict__ W1, const float* __restrict__ b1,
    const float* __restrict__ W2, const float* __restrict__ b2,
    const float* __restrict__ W3, const float* __restrict__ b3,
    float* __restrict__ out, int E, int N)
{
    int e = blockIdx.x * blockDim.x + threadIdx.x;
    if (e >= E) return;
    int u = src[e], v = dst[e];
    float h[128];
    for (int j = 0; j < 128; ++j) {
        float z = b1[j];
        const float* wj = W1 + j * 256;
        for (int k = 0; k < 64; ++k) {
            z += wj[k] * h1[(size_t)u * 64 + k]
               + wj[64 + k] * h1[(size_t)v * 64 + k]
               + (wj[128 + k] + wj[192 + k]) * h2[(size_t)u * 64 + k];
        }
        h[j] = 1.0f / (1.0f + __expf(-z));
    }
    float gg[128];
    for (int j = 0; j < 128; ++j) {
        float z = b2[j];
        for (int k = 0; k < 128; ++k) z = fmaf(W2[j * 128 + k], h[k], z);
        gg[j] = 1.0f / (1.0f + __expf(-z));
    }
    float s = b3[0];
    for (int j = 0; j < 128; ++j) s = fmaf(W3[j], gg[j], s);
    out[e] = s;
}

extern "C" void kernel_launch(void* const* d_in, const int* in_sizes, int n_in,
                              void* d_out, int out_size, void* d_ws, size_t ws_size,
                              hipStream_t stream) {
    const float* h1 = (const float*)d_in[0];
    const float* h2 = (const float*)d_in[1];
    const int*  src = (const int*)d_in[2];
    const int*  dst = (const int*)d_in[3];
    const float* W1 = (const float*)d_in[4];
    const float* b1 = (const float*)d_in[5];
    const float* W2 = (const float*)d_in[6];
    const float* b2 = (const float*)d_in[7];
    const float* W3 = (const float*)d_in[8];
    const float* b3 = (const float*)d_in[9];
    float* out = (float*)d_out;

    const int N = in_sizes[0] / 64;
    const int E = in_sizes[2];

    // workspace layout (float units)
    size_t offA   = 0;                         // N*64 dwords (bf16-pair packed)
    size_t offB   = offA + (size_t)N * 64;
    size_t offWCF = offB + (size_t)N * 64;     // 16384 ushorts
    size_t offWBF = offWCF + 8192;             // 8192 ushorts
    size_t offW2F = offWBF + 4096;             // 16384 ushorts
    size_t totalF = offW2F + 8192;

    if (ws_size < totalF * sizeof(float)) {
        naive_kernel<<<(E + 255) / 256, 256, 0, stream>>>(
            h1, h2, src, dst, W1, b1, W2, b2, W3, b3, out, E, N);
        return;
    }

    float* ws = (float*)d_ws;
    ushort* WCF = (ushort*)(ws + offWCF);
    ushort* WBF = (ushort*)(ws + offWBF);
    ushort* W2F = (ushort*)(ws + offW2F);

    prep_kernel<<<64, 256, 0, stream>>>(W1, W2, WCF, WBF, W2F);
    node_kernel<<<(N + 63) / 64, 256, 0, stream>>>(
        h1, h2, WCF, WBF, b1, (uint32_t*)(ws + offA), (uint32_t*)(ws + offB), N);
    const int ntiles = (E + 63) / 64;
    const int nblk = ntiles < 1024 ? ntiles : 1024;   // 4 blocks/CU (33.8KB LDS, 4 w/SIMD)
    edge_kernel<<<nblk, 256, 0, stream>>>(
        (const uint32_t*)(ws + offA), (const uint32_t*)(ws + offB), src, dst,
        W2F, b2, W3, b3, out, E, ntiles);
}